// Round 4
// baseline (351.127 us; speedup 1.0000x reference)
//
#include <hip/hip_runtime.h>
#include <hip/hip_cooperative_groups.h>
#include <cstddef>

namespace cg = cooperative_groups;

#define BATCH 64
#define HW 512
#define RVAL (1.0f / 512.0f)   // r = c = 1/512, exact in fp32
#define EPS_ 1e-6f
#define MAXIT 100
#define NBLK 256               // == CU count: cooperative launch always fits
#define NTHR 1024              // 16 waves/block, 1 block/CU

// Register-resident Sinkhorn: P = diag(u) * exp(-M) * diag(v).
// 256 blocks x 1024 threads: each thread holds 8 rows x 8 cols of K = exp(-M)
// in 64 VGPRs (16 float4, static indexing only). Iterations touch no K
// memory; the 4 blocks of a batch exchange 2 KB column partials per
// iteration via global memory + a per-batch device-scope counting barrier.
// __launch_bounds__(1024,4) is REQUIRED: a 1024-thread block needs 4
// waves/SIMD resident -> VGPR <= 128 or the launch itself is invalid.
__global__ __launch_bounds__(NTHR, 4)
void sinkhorn_reg3(const float* __restrict__ M, float* __restrict__ P,
                   float* __restrict__ colpart, int* __restrict__ bar) {
    const int tid = threadIdx.x;
    const int bid = blockIdx.x;
    const int b   = bid >> 2;      // batch index (4 blocks per batch)
    const int blk = bid & 3;       // 128-row slab within batch
    const int w   = tid >> 6;      // wave 0..15 (owns 8 rows)
    const int l   = tid & 63;      // lane 0..63 (owns 8 cols)

    cg::grid_group grid = cg::this_grid();

    __shared__ float v_lds[HW];         // current v (replicated per block)
    __shared__ float part[16][HW];      // per-wave column partials (32 KB)

    const int grow0 = b * HW + blk * 128 + w * 8;  // first of this thread's 8 rows
    const float* Mrow = M + (size_t)grow0 * HW + l * 8;

    // ---- one-time load: K = exp(-M) into registers ----
    float4 k4[16];
#pragma unroll
    for (int rr = 0; rr < 8; ++rr) {
        const float4* src = (const float4*)(Mrow + (size_t)rr * HW);
        float4 m0 = src[0], m1 = src[1];
        float4 a, c;
        a.x = __expf(-m0.x); a.y = __expf(-m0.y);
        a.z = __expf(-m0.z); a.w = __expf(-m0.w);
        c.x = __expf(-m1.x); c.y = __expf(-m1.y);
        c.z = __expf(-m1.z); c.w = __expf(-m1.w);
        k4[rr * 2] = a; k4[rr * 2 + 1] = c;
    }

    if (tid < HW) v_lds[tid] = 1.0f;
    __syncthreads();

    float u_loc[8];
    for (int it = 0; it < MAXIT; ++it) {
        // ---- phase A: u_i = r / (K v)_i  (row sums, in-register) ----
        float4 v0 = *(const float4*)&v_lds[l * 8];
        float4 v1 = *(const float4*)&v_lds[l * 8 + 4];
#pragma unroll
        for (int rr = 0; rr < 8; ++rr) {
            float4 a = k4[rr * 2], c = k4[rr * 2 + 1];
            float s = a.x * v0.x + a.y * v0.y + a.z * v0.z + a.w * v0.w
                    + c.x * v1.x + c.y * v1.y + c.z * v1.z + c.w * v1.w;
#pragma unroll
            for (int off = 32; off >= 1; off >>= 1) s += __shfl_xor(s, off, 64);
            u_loc[rr] = RVAL / s;      // replicated across the wave
        }

        // ---- phase B: column partials over this wave's 8 rows ----
        float4 p0 = make_float4(0.f, 0.f, 0.f, 0.f);
        float4 p1 = make_float4(0.f, 0.f, 0.f, 0.f);
#pragma unroll
        for (int rr = 0; rr < 8; ++rr) {
            float u = u_loc[rr];
            float4 a = k4[rr * 2], c = k4[rr * 2 + 1];
            p0.x += u * a.x; p0.y += u * a.y; p0.z += u * a.z; p0.w += u * a.w;
            p1.x += u * c.x; p1.y += u * c.y; p1.z += u * c.z; p1.w += u * c.w;
        }
        *(float4*)&part[w][l * 8]     = p0;
        *(float4*)&part[w][l * 8 + 4] = p1;
        __syncthreads();

        // ---- cross-wave reduce + publish this block's 512 column sums ----
        const int par = it & 1;   // double-buffered (barrier it+1 gates reuse)
        float* slot = colpart +
            ((size_t)par * BATCH * 4 + (size_t)b * 4 + blk) * HW;
        if (tid < HW) {
            float t = 0.f;
#pragma unroll
            for (int ww = 0; ww < 16; ++ww) t += part[ww][tid];
            slot[tid] = t;
        }
        __threadfence();                       // agent-scope: publish slot
        __syncthreads();
        int* bslot = bar + b * MAXIT + it;
        if (tid == 0) {
            __hip_atomic_fetch_add(bslot, 1, __ATOMIC_RELEASE,
                                   __HIP_MEMORY_SCOPE_AGENT);
            while (__hip_atomic_load(bslot, __ATOMIC_ACQUIRE,
                                     __HIP_MEMORY_SCOPE_AGENT) < 4)
                __builtin_amdgcn_s_sleep(2);
        }
        __syncthreads();

        // ---- combine the 4 slabs' partials; convergence; v update ----
        int viol = 0;
        float tt = 0.f;
        const float* base = colpart + ((size_t)par * BATCH * 4 + (size_t)b * 4) * HW;
        if (tid < HW) {
#pragma unroll
            for (int bb = 0; bb < 4; ++bb)
                tt += __hip_atomic_load(base + bb * HW + tid, __ATOMIC_ACQUIRE,
                                        __HIP_MEMORY_SCOPE_AGENT);
            viol = fabsf(v_lds[tid] * tt - RVAL) > EPS_;
        }
        int any = __syncthreads_or(viol);      // uniform across block & batch
        if (!any) break;           // keep row-normalized state (u_loc, v old)
        if (tid < HW) v_lds[tid] = RVAL / tt;  // col-normalize accepted
        __syncthreads();
    }

    // All P stores strictly after a grid-wide sync so the d_out-tail scratch
    // fallback can never be clobbered while another batch still iterates.
    grid.sync();

    // ---- final: P = diag(u) K diag(v), straight from registers ----
    float4 v0 = *(const float4*)&v_lds[l * 8];
    float4 v1 = *(const float4*)&v_lds[l * 8 + 4];
    float* Prow = P + (size_t)grow0 * HW + l * 8;
#pragma unroll
    for (int rr = 0; rr < 8; ++rr) {
        float u = u_loc[rr];
        float4 a = k4[rr * 2], c = k4[rr * 2 + 1];
        float4 o0, o1;
        o0.x = u * a.x * v0.x; o0.y = u * a.y * v0.y;
        o0.z = u * a.z * v0.z; o0.w = u * a.w * v0.w;
        o1.x = u * c.x * v1.x; o1.y = u * c.y * v1.y;
        o1.z = u * c.z * v1.z; o1.w = u * c.w * v1.w;
        float4* dst = (float4*)(Prow + (size_t)rr * HW);
        dst[0] = o0; dst[1] = o1;
    }
}

extern "C" void kernel_launch(void* const* d_in, const int* in_sizes, int n_in,
                              void* d_out, int out_size, void* d_ws, size_t ws_size,
                              hipStream_t stream) {
    const float* M = (const float*)d_in[0];
    float* P = (float*)d_out;

    const size_t CP_FLOATS = (size_t)2 * BATCH * 4 * HW;   // double-buffered partials
    const size_t BAR_INTS  = (size_t)BATCH * MAXIT;
    const size_t NEED = CP_FLOATS * sizeof(float) + BAR_INTS * sizeof(int);

    char* scratch;
    if (ws_size >= NEED) {
        scratch = (char*)d_ws;
    } else {
        // tail of d_out; safe because every P store happens after grid.sync()
        scratch = (char*)d_out + (size_t)out_size * sizeof(float) - NEED;
    }
    float* colpart = (float*)scratch;
    int*   bar     = (int*)(scratch + CP_FLOATS * sizeof(float));

    hipMemsetAsync(bar, 0, BAR_INTS * sizeof(int), stream);

    void* args[] = { (void*)&M, (void*)&P, (void*)&colpart, (void*)&bar };
    hipLaunchCooperativeKernel((const void*)sinkhorn_reg3, dim3(NBLK), dim3(NTHR),
                               args, 0, stream);
}

// Round 6
// 306.481 us; speedup vs baseline: 1.1457x; 1.1457x over previous
//
#include <hip/hip_runtime.h>
#include <hip/hip_cooperative_groups.h>
#include <cstddef>

namespace cg = cooperative_groups;

#define BATCH 64
#define HW 512
#define RVAL (1.0f / 512.0f)   // r = c = 1/512, exact in fp32
#define EPS_ 1e-6f
#define MAXIT 100
#define NBLK 256               // == CU count: cooperative launch always fits
#define NTHR 1024              // 16 waves/CU

// Fused single-pass streaming Sinkhorn: P = diag(u) * exp(-M) * diag(v).
// K is NOT cached in registers (rounds 2-4 proved it spills); it streams
// from L2/L3 once per iteration. Each pass computes u_i = r/(Kv)_i per row
// (shuffle reduce) and immediately accumulates u_i*K_ij column partials,
// so one 64 MB sweep does both marginals. 4 blocks per batch exchange 2 KB
// column partials via global + per-batch counting barrier (round-2/4
// machinery). M is read from HBM only on iteration 0; L3 (256 MB) holds it
// afterwards.
__global__ __launch_bounds__(NTHR, 4)
void sinkhorn_fused(const float* __restrict__ M, float* __restrict__ P,
                    float* __restrict__ colpart, int* __restrict__ bar,
                    int do_sync) {
    const int tid = threadIdx.x;
    const int bid = blockIdx.x;
    const int b   = bid >> 2;      // batch (4 blocks per batch)
    const int blk = bid & 3;       // 128-row slab
    const int w   = tid >> 6;      // wave 0..15 (owns 8 rows)
    const int l   = tid & 63;      // lane: owns cols [4l,4l+4) and [256+4l,..)

    cg::grid_group grid = cg::this_grid();

    __shared__ float v_lds[HW];        // current v
    __shared__ float part[16][HW];     // per-wave column partials (32 KB)

    const int grow0 = b * HW + blk * 128 + w * 8;
    const float4* Mrow = (const float4*)(M + (size_t)grow0 * HW);

    if (tid < HW) v_lds[tid] = 1.0f;
    __syncthreads();

    float u_loc[8];
    for (int it = 0; it < MAXIT; ++it) {
        float4 v0 = *(const float4*)&v_lds[l * 4];
        float4 v1 = *(const float4*)&v_lds[256 + l * 4];
        float4 cp0 = make_float4(0.f, 0.f, 0.f, 0.f);
        float4 cp1 = make_float4(0.f, 0.f, 0.f, 0.f);
#pragma unroll
        for (int rr = 0; rr < 8; ++rr) {
            float4 m0 = Mrow[rr * 128 + l];        // contiguous 1 KB / wave
            float4 m1 = Mrow[rr * 128 + 64 + l];   // second 1 KB
            float4 k0, k1;
            k0.x = __expf(-m0.x); k0.y = __expf(-m0.y);
            k0.z = __expf(-m0.z); k0.w = __expf(-m0.w);
            k1.x = __expf(-m1.x); k1.y = __expf(-m1.y);
            k1.z = __expf(-m1.z); k1.w = __expf(-m1.w);
            float s = k0.x * v0.x + k0.y * v0.y + k0.z * v0.z + k0.w * v0.w
                    + k1.x * v1.x + k1.y * v1.y + k1.z * v1.z + k1.w * v1.w;
#pragma unroll
            for (int off = 32; off >= 1; off >>= 1) s += __shfl_xor(s, off, 64);
            float u = RVAL / s;        // replicated across wave
            u_loc[rr] = u;
            cp0.x += u * k0.x; cp0.y += u * k0.y;
            cp0.z += u * k0.z; cp0.w += u * k0.w;
            cp1.x += u * k1.x; cp1.y += u * k1.y;
            cp1.z += u * k1.z; cp1.w += u * k1.w;
        }
        *(float4*)&part[w][l * 4]       = cp0;
        *(float4*)&part[w][256 + l * 4] = cp1;
        __syncthreads();

        // ---- publish this block's 512 column sums ----
        const int par = it & 1;   // double-buffered (barrier it+1 gates reuse)
        float* slot = colpart +
            ((size_t)par * BATCH * 4 + (size_t)b * 4 + blk) * HW;
        if (tid < HW) {
            float t = 0.f;
#pragma unroll
            for (int ww = 0; ww < 16; ++ww) t += part[ww][tid];
            slot[tid] = t;
        }
        __threadfence();                       // agent-scope: publish slot
        __syncthreads();
        int* bslot = bar + b * MAXIT + it;
        if (tid == 0) {
            __hip_atomic_fetch_add(bslot, 1, __ATOMIC_RELEASE,
                                   __HIP_MEMORY_SCOPE_AGENT);
            while (__hip_atomic_load(bslot, __ATOMIC_ACQUIRE,
                                     __HIP_MEMORY_SCOPE_AGENT) < 4)
                __builtin_amdgcn_s_sleep(8);
        }
        __syncthreads();

        // ---- combine 4 slabs; convergence; v update ----
        float tt = 0.f;
        int viol = 0;
        const float* base =
            colpart + ((size_t)par * BATCH * 4 + (size_t)b * 4) * HW;
        if (tid < HW) {
#pragma unroll
            for (int bb = 0; bb < 4; ++bb)
                tt += __hip_atomic_load(base + bb * HW + tid, __ATOMIC_ACQUIRE,
                                        __HIP_MEMORY_SCOPE_AGENT);
            viol = fabsf(v_lds[tid] * tt - RVAL) > EPS_;
        }
        int any = __syncthreads_or(viol);      // identical across batch blocks
        if (!any) break;           // converged: keep u_loc and old v
        if (tid < HW) v_lds[tid] = RVAL / tt;  // col-normalize accepted
        __syncthreads();
    }

    // Only needed when scratch lives in d_out's tail: ensure every batch
    // finished iterating before P stores overwrite that region.
    if (do_sync) grid.sync();

    // ---- final: P = diag(u) K diag(v); u_loc saved from converged iter ----
    float4 v0 = *(const float4*)&v_lds[l * 4];
    float4 v1 = *(const float4*)&v_lds[256 + l * 4];
    float4* Prow = (float4*)(P + (size_t)grow0 * HW);
#pragma unroll
    for (int rr = 0; rr < 8; ++rr) {
        float4 m0 = Mrow[rr * 128 + l];
        float4 m1 = Mrow[rr * 128 + 64 + l];
        float u = u_loc[rr];
        float4 o0, o1;
        o0.x = u * __expf(-m0.x) * v0.x; o0.y = u * __expf(-m0.y) * v0.y;
        o0.z = u * __expf(-m0.z) * v0.z; o0.w = u * __expf(-m0.w) * v0.w;
        o1.x = u * __expf(-m1.x) * v1.x; o1.y = u * __expf(-m1.y) * v1.y;
        o1.z = u * __expf(-m1.z) * v1.z; o1.w = u * __expf(-m1.w) * v1.w;
        Prow[rr * 128 + l]      = o0;
        Prow[rr * 128 + 64 + l] = o1;
    }
}

extern "C" void kernel_launch(void* const* d_in, const int* in_sizes, int n_in,
                              void* d_out, int out_size, void* d_ws, size_t ws_size,
                              hipStream_t stream) {
    const float* M = (const float*)d_in[0];
    float* P = (float*)d_out;

    const size_t CP_FLOATS = (size_t)2 * BATCH * 4 * HW;   // double-buffered
    const size_t BAR_INTS  = (size_t)BATCH * MAXIT;
    const size_t NEED = CP_FLOATS * sizeof(float) + BAR_INTS * sizeof(int);

    char* scratch;
    int do_sync;
    if (ws_size >= NEED) {
        scratch = (char*)d_ws;
        do_sync = 0;
    } else {
        // tail of d_out; P stores gated by grid.sync()
        scratch = (char*)d_out + (size_t)out_size * sizeof(float) - NEED;
        do_sync = 1;
    }
    float* colpart = (float*)scratch;
    int*   bar     = (int*)(scratch + CP_FLOATS * sizeof(float));

    hipMemsetAsync(bar, 0, BAR_INTS * sizeof(int), stream);

    void* args[] = { (void*)&M, (void*)&P, (void*)&colpart, (void*)&bar,
                     (void*)&do_sync };
    hipLaunchCooperativeKernel((const void*)sinkhorn_fused, dim3(NBLK),
                               dim3(NTHR), args, 0, stream);
}

// Round 7
// 136.984 us; speedup vs baseline: 2.5633x; 2.2374x over previous
//
#include <hip/hip_runtime.h>
#include <hip/hip_cooperative_groups.h>
#include <cstddef>

namespace cg = cooperative_groups;

#define BATCH 64
#define HW 512
#define RVAL (1.0f / 512.0f)   // r = c = 1/512, exact in fp32
#define EPS_ 1e-6f
#define MAXIT 100
#define NBLK 256               // == CU count: cooperative launch always fits
#define NTHR 1024              // 16 waves/block

// Private-batch Sinkhorn: P = diag(u) * exp(-M) * diag(v).
// Blocks 0..63 each own one full batch (512x512 = 1 MB) and iterate with ZERO
// inter-block communication -- no fences, no atomics, no global barriers in
// the loop (round-6 lesson: agent-scope fence/acquire per iteration was the
// 60 us/iter killer). Blocks 64..255 prefetch M into L3 meanwhile. One
// grid.sync hands (u,v) to the full-chip final pass (4 blocks/batch).
__global__ __launch_bounds__(NTHR, 4)
void sinkhorn_priv(const float* __restrict__ M, float* __restrict__ P,
                   float* __restrict__ uS, float* __restrict__ vS,
                   int do_sync2) {
    const int tid = threadIdx.x;
    const int bid = blockIdx.x;
    const int w   = tid >> 6;      // wave 0..15
    const int l   = tid & 63;      // lane: cols [4l,4l+4) and [256+4l,..)

    cg::grid_group grid = cg::this_grid();

    __shared__ float v_lds[HW];
    __shared__ float u_lds[HW];
    __shared__ float part[16][HW];   // per-wave column partials (32 KB)
    __shared__ float s_u[128];
    __shared__ float s_v[HW];

    if (bid < BATCH) {
        // ---------------- iterate one private batch ----------------
        const int b = bid;
        const float4* Mb = (const float4*)(M + (size_t)b * HW * HW);
        if (tid < HW) v_lds[tid] = 1.0f;
        __syncthreads();

        for (int it = 0; it < MAXIT; ++it) {
            float4 v0 = *(const float4*)&v_lds[l * 4];
            float4 v1 = *(const float4*)&v_lds[256 + l * 4];
            float4 cp0 = make_float4(0.f, 0.f, 0.f, 0.f);
            float4 cp1 = make_float4(0.f, 0.f, 0.f, 0.f);
            const float4* mp = Mb + (size_t)(w * 32) * 128;  // wave's 32 rows
#pragma unroll 4
            for (int rr = 0; rr < 32; ++rr) {
                float4 m0 = mp[l];
                float4 m1 = mp[64 + l];
                mp += 128;
                float4 k0, k1;
                k0.x = __expf(-m0.x); k0.y = __expf(-m0.y);
                k0.z = __expf(-m0.z); k0.w = __expf(-m0.w);
                k1.x = __expf(-m1.x); k1.y = __expf(-m1.y);
                k1.z = __expf(-m1.z); k1.w = __expf(-m1.w);
                float s = k0.x * v0.x + k0.y * v0.y + k0.z * v0.z + k0.w * v0.w
                        + k1.x * v1.x + k1.y * v1.y + k1.z * v1.z + k1.w * v1.w;
#pragma unroll
                for (int off = 32; off >= 1; off >>= 1)
                    s += __shfl_xor(s, off, 64);
                float u = RVAL / s;            // replicated in wave
                if (l == 0) u_lds[w * 32 + rr] = u;
                cp0.x += u * k0.x; cp0.y += u * k0.y;
                cp0.z += u * k0.z; cp0.w += u * k0.w;
                cp1.x += u * k1.x; cp1.y += u * k1.y;
                cp1.z += u * k1.z; cp1.w += u * k1.w;
            }
            *(float4*)&part[w][l * 4]       = cp0;
            *(float4*)&part[w][256 + l * 4] = cp1;
            __syncthreads();

            float tt = 0.f;
            int viol = 0;
            if (tid < HW) {
#pragma unroll
                for (int ww = 0; ww < 16; ++ww) tt += part[ww][tid];
                viol = fabsf(v_lds[tid] * tt - RVAL) > EPS_;
            }
            int any = __syncthreads_or(viol);
            if (!any) break;                   // keep u_lds and current v
            if (tid < HW) v_lds[tid] = RVAL / tt;
            __syncthreads();
        }

        // publish converged scalings for the full-chip final pass
        if (tid < HW) {
            uS[b * HW + tid] = u_lds[tid];
            vS[b * HW + tid] = v_lds[tid];
        }
        __threadfence();   // one agent-scope fence per kernel, not per iter
    } else {
        // ---------------- idle blocks: warm M into L3 ----------------
        const int idle = bid - BATCH;          // 0..191
        float acc = 0.f;
        for (int k = 0; k < 11; ++k) {
            int r = idle + 192 * (w + 16 * k); // strided full coverage
            if (r < BATCH * HW) {
                const float4* Mr = (const float4*)(M + (size_t)r * HW);
                float4 a = Mr[l], c2 = Mr[64 + l];
                acc += a.x + a.y + a.z + a.w + c2.x + c2.y + c2.z + c2.w;
            }
        }
        asm volatile("" :: "v"(acc));          // keep loads alive (rule #17)
    }

    grid.sync();   // single rendezvous: (u,v) published -> final pass

    // ---------------- final pass: all 256 blocks ----------------
    const int fb   = bid >> 2;     // batch
    const int slab = bid & 3;      // 128-row slab
    if (tid < 128)
        s_u[tid] = __hip_atomic_load(uS + fb * HW + slab * 128 + tid,
                                     __ATOMIC_RELAXED, __HIP_MEMORY_SCOPE_AGENT);
    if (tid < HW)
        s_v[tid] = __hip_atomic_load(vS + fb * HW + tid,
                                     __ATOMIC_RELAXED, __HIP_MEMORY_SCOPE_AGENT);
    __syncthreads();
    if (do_sync2) grid.sync();     // only when scratch aliases d_out tail

    const float4* Ms = (const float4*)(M + ((size_t)fb * HW + (size_t)slab * 128) * HW);
    float4*       Ps = (float4*)(P + ((size_t)fb * HW + (size_t)slab * 128) * HW);
    float4 v0 = *(const float4*)&s_v[l * 4];
    float4 v1 = *(const float4*)&s_v[256 + l * 4];
#pragma unroll
    for (int rr = 0; rr < 8; ++rr) {
        const int row = w * 8 + rr;
        float u = s_u[row];
        float4 m0 = Ms[row * 128 + l];
        float4 m1 = Ms[row * 128 + 64 + l];
        float4 o0, o1;
        o0.x = u * __expf(-m0.x) * v0.x; o0.y = u * __expf(-m0.y) * v0.y;
        o0.z = u * __expf(-m0.z) * v0.z; o0.w = u * __expf(-m0.w) * v0.w;
        o1.x = u * __expf(-m1.x) * v1.x; o1.y = u * __expf(-m1.y) * v1.y;
        o1.z = u * __expf(-m1.z) * v1.z; o1.w = u * __expf(-m1.w) * v1.w;
        Ps[row * 128 + l]      = o0;
        Ps[row * 128 + 64 + l] = o1;
    }
}

extern "C" void kernel_launch(void* const* d_in, const int* in_sizes, int n_in,
                              void* d_out, int out_size, void* d_ws, size_t ws_size,
                              hipStream_t stream) {
    const float* M = (const float*)d_in[0];
    float* P = (float*)d_out;

    const size_t NEED = (size_t)2 * BATCH * HW * sizeof(float);  // 256 KB u,v

    char* scratch;
    int do_sync2;
    if (ws_size >= NEED) {
        scratch = (char*)d_ws;
        do_sync2 = 0;
    } else {
        // tail of d_out; staged to LDS + grid.sync before P overwrites it
        scratch = (char*)d_out + (size_t)out_size * sizeof(float) - NEED;
        do_sync2 = 1;
    }
    float* uS = (float*)scratch;
    float* vS = uS + (size_t)BATCH * HW;

    void* args[] = { (void*)&M, (void*)&P, (void*)&uS, (void*)&vS,
                     (void*)&do_sync2 };
    hipLaunchCooperativeKernel((const void*)sinkhorn_priv, dim3(NBLK),
                               dim3(NTHR), args, 0, stream);
}